// Round 10
// baseline (133.968 us; speedup 1.0000x reference)
//
#include <hip/hip_runtime.h>

#define B_ 2048
#define S_ 512
#define T_ 17
#define REC 40
#define MAINB 64         // 64 main waves: each does fwd+bwd of its 32 seqs

typedef float v16f __attribute__((ext_vector_type(16)));
typedef short v8s  __attribute__((ext_vector_type(8)));
typedef float f4u  __attribute__((ext_vector_type(4), aligned(4)));

union frag_u { unsigned u[4]; v8s v; };

static __device__ inline unsigned pkbf(float lo, float hi) {
    unsigned r;
    asm("v_cvt_pk_bf16_f32 %0, %1, %2" : "=v"(r) : "v"(lo), "v"(hi));
    return r;
}

// ---- pack rows 0..15 (both halves) into B-fragment via permlane32_swap ----
#define PACKB(S0,S1,S2,S3,S4,S5,S6,S7, BOUT) do {                            \
    unsigned P0_ = pkbf(S0, S1), P1_ = pkbf(S2, S3);                         \
    unsigned R0_ = pkbf(S4, S5), R1_ = pkbf(S6, S7);                         \
    auto s0_ = __builtin_amdgcn_permlane32_swap(P0_, R0_, false, false);     \
    auto s1_ = __builtin_amdgcn_permlane32_swap(P1_, R1_, false, false);     \
    BOUT.u[0] = s0_[0]; BOUT.u[1] = s1_[0];                                  \
    BOUT.u[2] = s0_[1]; BOUT.u[3] = s1_[1];                                  \
} while (0)

#define W16SWAPA(W, w16) do {                                                \
    auto rw_ = __builtin_amdgcn_permlane32_swap(__float_as_uint(W[8]),       \
                                                __float_as_uint(W[8]),       \
                                                false, false);               \
    w16 = __uint_as_float(rw_[0]);                                           \
} while (0)

#define EXP9(dd_, Q0u, Q1u, Su) do {                                         \
    dd_[0]=__expf((Q0u).x); dd_[1]=__expf((Q0u).y);                          \
    dd_[2]=__expf((Q0u).z); dd_[3]=__expf((Q0u).w);                          \
    dd_[4]=__expf((Q1u).x); dd_[5]=__expf((Q1u).y);                          \
    dd_[6]=__expf((Q1u).z); dd_[7]=__expf((Q1u).w);                          \
    dd_[8]=__expf(Su);                                                       \
} while (0)

// ---- forward step: W' = (E^T W) o d, mask-gated (r8-validated math) ----
#define FSTEPA(W, w16, Z, A1, E16, Q0u, Q1u, Su, Mu) do {                    \
    frag_u Bf_;                                                              \
    PACKB(W[0],W[1],W[2],W[3],W[4],W[5],W[6],W[7], Bf_);                     \
    v16f acc_ = __builtin_amdgcn_mfma_f32_32x32x16_bf16(A1.v, Bf_.v, zacc,0,0,0); \
    float dd_[9]; EXP9(dd_, Q0u, Q1u, Su);                                   \
    bool bm_ = (Mu) != 0;                                                    \
    _Pragma("unroll") for (int k_ = 0; k_ < 9; ++k_) {                       \
        float n_ = fmaf(E16[k_], w16, acc_[k_]) * dd_[k_];                   \
        W[k_] = bm_ ? n_ : W[k_];                                            \
    }                                                                        \
    W16SWAPA(W, w16);                                                        \
} while (0)

// ---- backward step: v' = E (d o v), mask-gated (r8-validated math) ----
#define BSTEPA(W, w16, Z, A1, E16, Q0u, Q1u, Su, Mu) do {                    \
    float dd_[9]; EXP9(dd_, Q0u, Q1u, Su);                                   \
    float U16_ = w16 * dd_[8];                                               \
    frag_u Bf_;                                                              \
    PACKB(W[0]*dd_[0], W[1]*dd_[1], W[2]*dd_[2], W[3]*dd_[3],                \
          W[4]*dd_[4], W[5]*dd_[5], W[6]*dd_[6], W[7]*dd_[7], Bf_);          \
    v16f acc_ = __builtin_amdgcn_mfma_f32_32x32x16_bf16(A1.v, Bf_.v, zacc,0,0,0); \
    bool bm_ = (Mu) != 0;                                                    \
    _Pragma("unroll") for (int k_ = 0; k_ < 9; ++k_) {                       \
        float n_ = fmaf(E16[k_], U16_, acc_[k_]);                            \
        W[k_] = bm_ ? n_ : W[k_];                                            \
    }                                                                        \
    W16SWAPA(W, w16);                                                        \
} while (0)

#define RENORMA(W, w16, Z) do {                                              \
    float M_ = fmaxf(fmaxf(fmaxf(W[0],W[1]),fmaxf(W[2],W[3])),               \
                     fmaxf(fmaxf(W[4],W[5]),fmaxf(fmaxf(W[6],W[7]),W[8])));  \
    auto rm_ = __builtin_amdgcn_permlane32_swap(__float_as_uint(M_),         \
                                                __float_as_uint(M_),         \
                                                false, false);               \
    M_ = fmaxf(__uint_as_float(rm_[0]), __uint_as_float(rm_[1]));            \
    float r_ = 1.0f / M_;                                                    \
    Z += __logf(M_);                                                         \
    _Pragma("unroll") for (int k_ = 0; k_ < 9; ++k_) W[k_] *= r_;            \
    w16 *= r_;                                                               \
} while (0)

// ---- load one 4-step chunk (lane's 9 rows) + mask ----
#define LOADC(Q0, Q1, SS, MM, T0_) do {                                      \
    const float* bp_ = ip + (size_t)(T0_) * T_;                              \
    _Pragma("unroll") for (int u_ = 0; u_ < 4; ++u_) {                       \
        Q0[u_] = *(const f4u*)(bp_ + u_ * T_ + 4 * h);                       \
        Q1[u_] = *(const f4u*)(bp_ + u_ * T_ + 8 + 4 * h);                   \
        SS[u_] = bp_[u_ * T_ + 16];                                          \
    }                                                                        \
    MM = *(const int4*)(mp + (T0_));                                         \
} while (0)

// chunk n: P base 4n (ascending), Q base 508-4n (consumed descending)
#define LOADX(n_) do { LOADC(XP0,XP1,XPS,XPM, 4*(n_));                       \
                       LOADC(XQ0,XQ1,XQS,XQM, 508-4*(n_)); } while (0)
#define LOADY(n_) do { LOADC(YP0,YP1,YPS,YPM, 4*(n_));                       \
                       LOADC(YQ0,YQ1,YQS,YQM, 508-4*(n_)); } while (0)

// one interleaved chunk: 4 fwd steps (P) + 4 bwd steps (Q), then renorms
#define FCH2(P0,P1,PS,PM, Q0,Q1,QS,QM) do {                                  \
    FSTEPA(WP, wp16, ZP, A1f, E16f, P0[0], P1[0], PS[0], (PM).x);            \
    BSTEPA(WQ, wq16, ZQ, A1b, E16b, Q0[3], Q1[3], QS[3], (QM).w);            \
    FSTEPA(WP, wp16, ZP, A1f, E16f, P0[1], P1[1], PS[1], (PM).y);            \
    BSTEPA(WQ, wq16, ZQ, A1b, E16b, Q0[2], Q1[2], QS[2], (QM).z);            \
    FSTEPA(WP, wp16, ZP, A1f, E16f, P0[2], P1[2], PS[2], (PM).z);            \
    BSTEPA(WQ, wq16, ZQ, A1b, E16b, Q0[1], Q1[1], QS[1], (QM).y);            \
    FSTEPA(WP, wp16, ZP, A1f, E16f, P0[3], P1[3], PS[3], (PM).w);            \
    BSTEPA(WQ, wq16, ZQ, A1b, E16b, Q0[0], Q1[0], QS[0], (QM).x);            \
    RENORMA(WP, wp16, ZP);                                                   \
    RENORMA(WQ, wq16, ZQ);                                                   \
} while (0)

#define FCHX() FCH2(XP0,XP1,XPS,XPM, XQ0,XQ1,XQS,XQM)
#define FCHY() FCH2(YP0,YP1,YPS,YPM, YQ0,YQ1,YQS,YQM)

__global__ __launch_bounds__(64, 1) void crf_fused(
    const float* __restrict__ inputs,   // [B,S,T]
    const int*   __restrict__ tags,     // [B,S]
    const int*   __restrict__ mask,     // [B,S]
    const float* __restrict__ trans,    // [T,T]
    const float* __restrict__ startt,   // [T]
    const float* __restrict__ endt,     // [T]
    float* __restrict__ ws)             // [B][REC]
{
    __shared__ float tl[T_ * T_];
    const int lane = (int)threadIdx.x;
    const int bid = (int)blockIdx.x;
    for (int k = lane; k < T_ * T_; k += 64) tl[k] = trans[k];
    __syncthreads();

    if (bid < MAINB) {
        // ===== MAIN: fwd chain (t 0..255) + bwd chain (t 511..256), same wave =====
        const int h = lane >> 5;        // half
        const int col = lane & 31;      // seq column (and A row)
        const int seq = bid * 32 + col;

        // A fragments: fwd A = E^T padded, bwd A = E padded (k=0..15)
        frag_u A1f, A1b;
#pragma unroll
        for (int wd = 0; wd < 4; ++wd) {
            const int k0 = 8 * h + 2 * wd, k1 = k0 + 1;
            float f0 = 0.0f, f1 = 0.0f, b0 = 0.0f, b1 = 0.0f;
            if (col < 17) {
                f0 = __expf(tl[k0 * T_ + col]); f1 = __expf(tl[k1 * T_ + col]);
                b0 = __expf(tl[col * T_ + k0]); b1 = __expf(tl[col * T_ + k1]);
            }
            A1f.u[wd] = pkbf(f0, f1);
            A1b.u[wd] = pkbf(b0, b1);
        }
        // k=16 rank-1 coefficients, per lane's 9 rows
        float E16f[9], E16b[9];
#pragma unroll
        for (int k = 0; k < 4; ++k) {
            const int r0 = 4 * h + k, r1 = 8 + 4 * h + k;
            E16f[k]     = __expf(tl[16 * T_ + r0]);
            E16f[4 + k] = __expf(tl[16 * T_ + r1]);
            E16b[k]     = __expf(tl[r0 * T_ + 16]);
            E16b[4 + k] = __expf(tl[r1 * T_ + 16]);
        }
        E16f[8] = (h == 0) ? __expf(tl[16 * T_ + 16]) : 0.0f;
        E16b[8] = E16f[8];

        v16f zacc;
#pragma unroll
        for (int r = 0; r < 16; ++r) zacc[r] = 0.0f;

        const float* ip = inputs + (size_t)seq * (S_ * T_);
        const int*   mp = mask + (size_t)seq * S_;

        float WP[9], wp16, ZP = 0.0f;   // fwd state
        float WQ[9], wq16, ZQ = 0.0f;   // bwd state

        f4u XP0[4], XP1[4]; float XPS[4]; int4 XPM;
        f4u YP0[4], YP1[4]; float YPS[4]; int4 YPM;
        f4u XQ0[4], XQ1[4]; float XQS[4]; int4 XQM;
        f4u YQ0[4], YQ1[4]; float YQS[4]; int4 YQM;

        LOADX(0); LOADY(1);
        {   // init fwd: alpha0 = exp(logit0 + start)
            f4u s0 = *(const f4u*)(startt + 4 * h);
            f4u s1 = *(const f4u*)(startt + 8 + 4 * h);
            WP[0] = __expf(XP0[0].x + s0.x); WP[1] = __expf(XP0[0].y + s0.y);
            WP[2] = __expf(XP0[0].z + s0.z); WP[3] = __expf(XP0[0].w + s0.w);
            WP[4] = __expf(XP1[0].x + s1.x); WP[5] = __expf(XP1[0].y + s1.y);
            WP[6] = __expf(XP1[0].z + s1.z); WP[7] = __expf(XP1[0].w + s1.w);
            WP[8] = h ? 0.0f : __expf(XPS[0] + startt[16]);
            W16SWAPA(WP, wp16);
        }
        {   // init bwd: v_511 = exp(end)
            f4u e0 = *(const f4u*)(endt + 4 * h);
            f4u e1 = *(const f4u*)(endt + 8 + 4 * h);
            WQ[0] = __expf(e0.x); WQ[1] = __expf(e0.y);
            WQ[2] = __expf(e0.z); WQ[3] = __expf(e0.w);
            WQ[4] = __expf(e1.x); WQ[5] = __expf(e1.y);
            WQ[6] = __expf(e1.z); WQ[7] = __expf(e1.w);
            WQ[8] = h ? 0.0f : __expf(endt[16]);
            W16SWAPA(WQ, wq16);
        }
        // chunk 0: fwd steps t=1..3 (t=0 consumed by init), bwd steps t=511..508
        FSTEPA(WP, wp16, ZP, A1f, E16f, XP0[1], XP1[1], XPS[1], XPM.y);
        BSTEPA(WQ, wq16, ZQ, A1b, E16b, XQ0[3], XQ1[3], XQS[3], XQM.w);
        FSTEPA(WP, wp16, ZP, A1f, E16f, XP0[2], XP1[2], XPS[2], XPM.z);
        BSTEPA(WQ, wq16, ZQ, A1b, E16b, XQ0[2], XQ1[2], XQS[2], XQM.z);
        FSTEPA(WP, wp16, ZP, A1f, E16f, XP0[3], XP1[3], XPS[3], XPM.w);
        BSTEPA(WQ, wq16, ZQ, A1b, E16b, XQ0[1], XQ1[1], XQS[1], XQM.y);
        BSTEPA(WQ, wq16, ZQ, A1b, E16b, XQ0[0], XQ1[0], XQS[0], XQM.x);
        RENORMA(WP, wp16, ZP);
        RENORMA(WQ, wq16, ZQ);

        LOADX(2);
        FCHY();                               // chunk 1
        for (int cp = 1; cp < 31; ++cp) {
            LOADY(2 * cp + 1);
            FCHX();                           // chunk 2cp
            LOADX(2 * cp + 2);
            FCHY();                           // chunk 2cp+1
        }
        LOADY(63);
        FCHX();                               // chunk 62
        FCHY();                               // chunk 63 -> alpha_255, v_255

        float* rec = ws + (size_t)seq * REC;
#pragma unroll
        for (int k = 0; k < 4; ++k) {
            rec[4 * h + k]      = WP[k];
            rec[8 + 4 * h + k]  = WP[4 + k];
            rec[18 + 4 * h + k] = WQ[k];
            rec[26 + 4 * h + k] = WQ[4 + k];
        }
        if (h == 0) {
            rec[16] = WP[8]; rec[17] = ZP;
            rec[34] = WQ[8]; rec[35] = ZQ;
        }
    } else {
        // ===== HELPER: per-seq path score (1 seq / wave) — r5/r6/r8-validated =====
        const int s = bid - MAINB;
        const int* tp = tags + (size_t)s * S_;
        const int* mp = mask + (size_t)s * S_;
        const float* ib = inputs + (size_t)s * (S_ * T_);
        const int4* tp4 = (const int4*)tp;
        const int4* mp4 = (const int4*)mp;

        int4 t0 = tp4[2 * lane], t1 = tp4[2 * lane + 1];
        int4 m0 = mp4[2 * lane], m1 = mp4[2 * lane + 1];
        int tg[8] = {t0.x, t0.y, t0.z, t0.w, t1.x, t1.y, t1.z, t1.w};
        int mi[8] = {m0.x, m0.y, m0.z, m0.w, m1.x, m1.y, m1.z, m1.w};
        int tprev = (lane > 0) ? tp[8 * lane - 1] : 0;

        float e = 0.0f, tr = 0.0f;
        int ms = 0;
#pragma unroll
        for (int u = 0; u < 8; ++u) {
            int t = 8 * lane + u;
            float mf = (float)mi[u];
            float gate = (t <= S_ - 2) ? mf : 0.0f;
            e = fmaf(gate, ib[(size_t)t * T_ + tg[u]], e);
            int pt = (u == 0) ? tprev : tg[u - 1];
            float tv = tl[pt * T_ + tg[u]];
            tr = fmaf((t >= 1) ? mf : 0.0f, tv, tr);
            ms += mi[u];
        }
        for (int d = 1; d < 64; d <<= 1) {
            e  += __shfl_xor(e, d);
            tr += __shfl_xor(tr, d);
            ms += __shfl_xor(ms, d);
        }
        if (lane == 0) {
            int li = ms - 1; if (li < 0) li = 0;
            int lt = tp[li];
            float ml = (float)mp[S_ - 1];
            float lin = ib[(size_t)(S_ - 1) * T_ + lt];
            float sc = startt[tp[0]] + tr + e + endt[lt] + lin * ml;
            ws[(size_t)s * REC + 36] = sc;
        }
    }
}

__global__ __launch_bounds__(256) void crf_final(const float* __restrict__ ws,
                                                 float* __restrict__ out)
{
    __shared__ float sm[256];
    const int tid = (int)threadIdx.x;
    float a = 0.0f;
    for (int s = tid; s < B_; s += 256) {
        const float* r = ws + (size_t)s * REC;
        float dot = 0.0f;
#pragma unroll
        for (int i = 0; i < T_; ++i) dot = fmaf(r[i], r[18 + i], dot);
        a += r[36] - (r[17] + r[35] + __logf(dot));
    }
    sm[tid] = a;
    __syncthreads();
    for (int k = 128; k >= 1; k >>= 1) {
        if (tid < k) sm[tid] += sm[tid + k];
        __syncthreads();
    }
    if (tid == 0) out[0] = sm[0];
}

extern "C" void kernel_launch(void* const* d_in, const int* in_sizes, int n_in,
                              void* d_out, int out_size, void* d_ws, size_t ws_size,
                              hipStream_t stream)
{
    const float* inputs = (const float*)d_in[0];
    const int*   tags   = (const int*)d_in[1];
    const int*   mask   = (const int*)d_in[2];
    const float* trans  = (const float*)d_in[3];
    const float* startt = (const float*)d_in[4];
    const float* endt   = (const float*)d_in[5];
    float* out = (float*)d_out;
    float* ws  = (float*)d_ws;

    crf_fused<<<MAINB + B_, 64, 0, stream>>>(inputs, tags, mask, trans,
                                             startt, endt, ws);
    crf_final<<<1, 256, 0, stream>>>(ws, out);
}

// Round 11
// 97.752 us; speedup vs baseline: 1.3705x; 1.3705x over previous
//
#include <hip/hip_runtime.h>

#define B_ 2048
#define S_ 512
#define T_ 17
#define REC 40
#define FWDB 64
#define MAINB 128
#define DRO 20            // ushorts per d-row (17 bf16 + 3 pad -> 40B, 8B-aligned)
#define PREPCB 4096       // conversion blocks (64 thr each)

typedef float v16f __attribute__((ext_vector_type(16)));
typedef short v8s  __attribute__((ext_vector_type(8)));
typedef float f4u  __attribute__((ext_vector_type(4), aligned(4)));

union frag_u { unsigned u[4]; v8s v; };

static __device__ inline unsigned pkbf(float lo, float hi) {
    unsigned r;
    asm("v_cvt_pk_bf16_f32 %0, %1, %2" : "=v"(r) : "v"(lo), "v"(hi));
    return r;
}
static __device__ inline float bflo(unsigned u) { return __uint_as_float(u << 16); }
static __device__ inline float bfhi(unsigned u) { return __uint_as_float(u & 0xffff0000u); }

// ---- shared: pack 16 values (both halves) into B-fragment via permlane32_swap ----
#define PACKB(S0,S1,S2,S3,S4,S5,S6,S7, BOUT) do {                            \
    unsigned P0_ = pkbf(S0, S1), P1_ = pkbf(S2, S3);                         \
    unsigned R0_ = pkbf(S4, S5), R1_ = pkbf(S6, S7);                         \
    auto s0_ = __builtin_amdgcn_permlane32_swap(P0_, R0_, false, false);     \
    auto s1_ = __builtin_amdgcn_permlane32_swap(P1_, R1_, false, false);     \
    BOUT.u[0] = s0_[0]; BOUT.u[1] = s1_[0];                                  \
    BOUT.u[2] = s0_[1]; BOUT.u[3] = s1_[1];                                  \
} while (0)

// ======================= FAST PATH (exp-free chain) =======================

#define W16SWAPW() do {                                                      \
    auto rw_ = __builtin_amdgcn_permlane32_swap(__float_as_uint(W[8]),       \
                                                __float_as_uint(W[8]),       \
                                                false, false);               \
    w16 = __uint_as_float(rw_[0]);                                           \
} while (0)

#define CVT9(dd_, A2_, B2_, SU_) do {                                        \
    dd_[0]=bflo((A2_).x); dd_[1]=bfhi((A2_).x);                              \
    dd_[2]=bflo((A2_).y); dd_[3]=bfhi((A2_).y);                              \
    dd_[4]=bflo((B2_).x); dd_[5]=bfhi((B2_).x);                              \
    dd_[6]=bflo((B2_).y); dd_[7]=bfhi((B2_).y);                              \
    dd_[8]=bflo(SU_);                                                        \
} while (0)

#define FSTEPD(A2_, B2_, SU_, Mu) do {                                       \
    frag_u Bf_;                                                              \
    PACKB(W[0],W[1],W[2],W[3],W[4],W[5],W[6],W[7], Bf_);                     \
    v16f acc_ = __builtin_amdgcn_mfma_f32_32x32x16_bf16(A1.v, Bf_.v, zacc,0,0,0); \
    float dd_[9]; CVT9(dd_, A2_, B2_, SU_);                                  \
    bool bm_ = (Mu) != 0;                                                    \
    _Pragma("unroll") for (int k_ = 0; k_ < 9; ++k_) {                       \
        float n_ = fmaf(E16[k_], w16, acc_[k_]) * dd_[k_];                   \
        W[k_] = bm_ ? n_ : W[k_];                                            \
    }                                                                        \
    W16SWAPW();                                                              \
} while (0)

#define BSTEPD(A2_, B2_, SU_, Mu) do {                                       \
    float dd_[9]; CVT9(dd_, A2_, B2_, SU_);                                  \
    float U16_ = w16 * dd_[8];                                               \
    frag_u Bf_;                                                              \
    PACKB(W[0]*dd_[0], W[1]*dd_[1], W[2]*dd_[2], W[3]*dd_[3],                \
          W[4]*dd_[4], W[5]*dd_[5], W[6]*dd_[6], W[7]*dd_[7], Bf_);          \
    v16f acc_ = __builtin_amdgcn_mfma_f32_32x32x16_bf16(A1.v, Bf_.v, zacc,0,0,0); \
    bool bm_ = (Mu) != 0;                                                    \
    _Pragma("unroll") for (int k_ = 0; k_ < 9; ++k_) {                       \
        float n_ = fmaf(E16[k_], U16_, acc_[k_]);                            \
        W[k_] = bm_ ? n_ : W[k_];                                            \
    }                                                                        \
    W16SWAPW();                                                              \
} while (0)

#define RENORMD() do {                                                       \
    float M_ = fmaxf(fmaxf(fmaxf(W[0],W[1]),fmaxf(W[2],W[3])),               \
                     fmaxf(fmaxf(W[4],W[5]),fmaxf(fmaxf(W[6],W[7]),W[8])));  \
    auto rm_ = __builtin_amdgcn_permlane32_swap(__float_as_uint(M_),         \
                                                __float_as_uint(M_),         \
                                                false, false);               \
    M_ = fmaxf(__uint_as_float(rm_[0]), __uint_as_float(rm_[1]));            \
    float r_ = 1.0f / M_;                                                    \
    Z += __logf(M_);                                                         \
    _Pragma("unroll") for (int k_ = 0; k_ < 9; ++k_) W[k_] *= r_;            \
    w16 *= r_;                                                               \
} while (0)

#define LOADD8(DA, DB, DS, MA, MB, T0_) do {                                 \
    const unsigned short* rp_ = dp + (size_t)(T0_) * DRO;                    \
    _Pragma("unroll") for (int u_ = 0; u_ < 8; ++u_) {                       \
        DA[u_] = *(const uint2*)(rp_ + u_ * DRO + 4 * h);                    \
        DB[u_] = *(const uint2*)(rp_ + u_ * DRO + 8 + 4 * h);                \
        DS[u_] = *(const unsigned*)(rp_ + u_ * DRO + 16);                    \
    }                                                                        \
    MA = *(const int4*)(mp + (T0_));                                         \
    MB = *(const int4*)(mp + (T0_) + 4);                                     \
} while (0)

#define DFCH8(DA, DB, DS, MA, MB) do {                                       \
    FSTEPD(DA[0], DB[0], DS[0], (MA).x);                                     \
    FSTEPD(DA[1], DB[1], DS[1], (MA).y);                                     \
    FSTEPD(DA[2], DB[2], DS[2], (MA).z);                                     \
    FSTEPD(DA[3], DB[3], DS[3], (MA).w);                                     \
    RENORMD();                                                               \
    FSTEPD(DA[4], DB[4], DS[4], (MB).x);                                     \
    FSTEPD(DA[5], DB[5], DS[5], (MB).y);                                     \
    FSTEPD(DA[6], DB[6], DS[6], (MB).z);                                     \
    FSTEPD(DA[7], DB[7], DS[7], (MB).w);                                     \
    RENORMD();                                                               \
} while (0)

#define DBCH8(DA, DB, DS, MA, MB) do {                                       \
    BSTEPD(DA[7], DB[7], DS[7], (MB).w);                                     \
    BSTEPD(DA[6], DB[6], DS[6], (MB).z);                                     \
    BSTEPD(DA[5], DB[5], DS[5], (MB).y);                                     \
    BSTEPD(DA[4], DB[4], DS[4], (MB).x);                                     \
    RENORMD();                                                               \
    BSTEPD(DA[3], DB[3], DS[3], (MA).w);                                     \
    BSTEPD(DA[2], DB[2], DS[2], (MA).z);                                     \
    BSTEPD(DA[1], DB[1], DS[1], (MA).y);                                     \
    BSTEPD(DA[0], DB[0], DS[0], (MA).x);                                     \
    RENORMD();                                                               \
} while (0)

// ---- shared helper: per-seq path score (r5/r6/r8-validated) ----
static __device__ void helper_score(int s, int lane,
                                    const int* __restrict__ tags,
                                    const int* __restrict__ mask,
                                    const float* __restrict__ inputs,
                                    const float* __restrict__ startt,
                                    const float* __restrict__ endt,
                                    const float* tl, float* recs)
{
    const int* tp = tags + (size_t)s * S_;
    const int* mp = mask + (size_t)s * S_;
    const float* ib = inputs + (size_t)s * (S_ * T_);
    const int4* tp4 = (const int4*)tp;
    const int4* mp4 = (const int4*)mp;

    int4 t0 = tp4[2 * lane], t1 = tp4[2 * lane + 1];
    int4 m0 = mp4[2 * lane], m1 = mp4[2 * lane + 1];
    int tg[8] = {t0.x, t0.y, t0.z, t0.w, t1.x, t1.y, t1.z, t1.w};
    int mi[8] = {m0.x, m0.y, m0.z, m0.w, m1.x, m1.y, m1.z, m1.w};
    int tprev = (lane > 0) ? tp[8 * lane - 1] : 0;

    float e = 0.0f, tr = 0.0f;
    int ms = 0;
#pragma unroll
    for (int u = 0; u < 8; ++u) {
        int t = 8 * lane + u;
        float mf = (float)mi[u];
        float gate = (t <= S_ - 2) ? mf : 0.0f;
        e = fmaf(gate, ib[(size_t)t * T_ + tg[u]], e);
        int pt = (u == 0) ? tprev : tg[u - 1];
        float tv = tl[pt * T_ + tg[u]];
        tr = fmaf((t >= 1) ? mf : 0.0f, tv, tr);
        ms += mi[u];
    }
    for (int d = 1; d < 64; d <<= 1) {
        e  += __shfl_xor(e, d);
        tr += __shfl_xor(tr, d);
        ms += __shfl_xor(ms, d);
    }
    if (lane == 0) {
        int li = ms - 1; if (li < 0) li = 0;
        int lt = tp[li];
        float ml = (float)mp[S_ - 1];
        float lin = ib[(size_t)(S_ - 1) * T_ + lt];
        float sc = startt[tp[0]] + tr + e + endt[lt] + lin * ml;
        recs[(size_t)s * REC + 36] = sc;
    }
}

// ---- pre-pass: d = exp(inputs) as bf16 [B,S,20]; + helper scores ----
__global__ __launch_bounds__(64) void crf_prep(
    const float* __restrict__ inputs, const int* __restrict__ tags,
    const int* __restrict__ mask, const float* __restrict__ trans,
    const float* __restrict__ startt, const float* __restrict__ endt,
    float* __restrict__ recs, unsigned short* __restrict__ dws)
{
    __shared__ float tl[T_ * T_];
    const int lane = (int)threadIdx.x;
    const int bid = (int)blockIdx.x;
    for (int k = lane; k < T_ * T_; k += 64) tl[k] = trans[k];
    __syncthreads();

    if (bid < PREPCB) {
        for (int r = bid * 64 + lane; r < B_ * S_; r += PREPCB * 64) {
            const float* src = inputs + (size_t)r * T_;
            f4u x0 = *(const f4u*)src,       x1 = *(const f4u*)(src + 4);
            f4u x2 = *(const f4u*)(src + 8), x3 = *(const f4u*)(src + 12);
            float s16 = src[16];
            unsigned u0 = pkbf(__expf(x0.x), __expf(x0.y));
            unsigned u1 = pkbf(__expf(x0.z), __expf(x0.w));
            unsigned u2 = pkbf(__expf(x1.x), __expf(x1.y));
            unsigned u3 = pkbf(__expf(x1.z), __expf(x1.w));
            unsigned u4 = pkbf(__expf(x2.x), __expf(x2.y));
            unsigned u5 = pkbf(__expf(x2.z), __expf(x2.w));
            unsigned u6 = pkbf(__expf(x3.x), __expf(x3.y));
            unsigned u7 = pkbf(__expf(x3.z), __expf(x3.w));
            unsigned u8 = pkbf(__expf(s16), 0.0f);
            uint2* dst = (uint2*)(dws + (size_t)r * DRO);
            uint2 t_;
            t_.x = u0; t_.y = u1; dst[0] = t_;
            t_.x = u2; t_.y = u3; dst[1] = t_;
            t_.x = u4; t_.y = u5; dst[2] = t_;
            t_.x = u6; t_.y = u7; dst[3] = t_;
            t_.x = u8; t_.y = 0u; dst[4] = t_;
        }
    } else {
        helper_score(bid - PREPCB, lane, tags, mask, inputs, startt, endt, tl, recs);
    }
}

// ---- main: MFMA scaled recurrence on precomputed d, exp-free chain ----
__global__ __launch_bounds__(64) void crf_main2(
    const unsigned short* __restrict__ dws, const int* __restrict__ mask,
    const float* __restrict__ trans, const float* __restrict__ startt,
    const float* __restrict__ endt, float* __restrict__ recs)
{
    __shared__ float tl[T_ * T_];
    const int lane = (int)threadIdx.x;
    const int bid = (int)blockIdx.x;
    for (int k = lane; k < T_ * T_; k += 64) tl[k] = trans[k];
    __syncthreads();

    const bool isF = (bid < FWDB);
    const int h = lane >> 5;
    const int col = lane & 31;
    const int seq = (isF ? bid : bid - FWDB) * 32 + col;

    frag_u A1;
#pragma unroll
    for (int wd = 0; wd < 4; ++wd) {
        const int k0 = 8 * h + 2 * wd, k1 = k0 + 1;
        float e0 = 0.0f, e1 = 0.0f;
        if (col < 17) {
            e0 = isF ? __expf(tl[k0 * T_ + col]) : __expf(tl[col * T_ + k0]);
            e1 = isF ? __expf(tl[k1 * T_ + col]) : __expf(tl[col * T_ + k1]);
        }
        A1.u[wd] = pkbf(e0, e1);
    }
    float E16[9];
#pragma unroll
    for (int k = 0; k < 4; ++k) {
        const int r0 = 4 * h + k, r1 = 8 + 4 * h + k;
        E16[k]     = __expf(isF ? tl[16 * T_ + r0] : tl[r0 * T_ + 16]);
        E16[4 + k] = __expf(isF ? tl[16 * T_ + r1] : tl[r1 * T_ + 16]);
    }
    E16[8] = (h == 0) ? __expf(tl[16 * T_ + 16]) : 0.0f;

    v16f zacc;
#pragma unroll
    for (int r = 0; r < 16; ++r) zacc[r] = 0.0f;

    const unsigned short* dp = dws + (size_t)seq * (S_ * DRO);
    const int* mp = mask + (size_t)seq * S_;

    float W[9], w16, Z = 0.0f;
    uint2 XA[8], XB[8]; unsigned XS[8]; int4 XM0, XM1;
    uint2 YA[8], YB[8]; unsigned YS[8]; int4 YM0, YM1;

    if (isF) {
        LOADD8(XA, XB, XS, XM0, XM1, 0);
        LOADD8(YA, YB, YS, YM0, YM1, 8);
        {   // init: alpha0 = d0 * exp(start)
            float dd0[9]; CVT9(dd0, XA[0], XB[0], XS[0]);
            f4u s0 = *(const f4u*)(startt + 4 * h);
            f4u s1 = *(const f4u*)(startt + 8 + 4 * h);
            W[0] = dd0[0] * __expf(s0.x); W[1] = dd0[1] * __expf(s0.y);
            W[2] = dd0[2] * __expf(s0.z); W[3] = dd0[3] * __expf(s0.w);
            W[4] = dd0[4] * __expf(s1.x); W[5] = dd0[5] * __expf(s1.y);
            W[6] = dd0[6] * __expf(s1.z); W[7] = dd0[7] * __expf(s1.w);
            W[8] = h ? 0.0f : dd0[8] * __expf(startt[16]);
            W16SWAPW();
        }
        FSTEPD(XA[1], XB[1], XS[1], XM0.y);
        FSTEPD(XA[2], XB[2], XS[2], XM0.z);
        FSTEPD(XA[3], XB[3], XS[3], XM0.w);
        RENORMD();
        FSTEPD(XA[4], XB[4], XS[4], XM1.x);
        FSTEPD(XA[5], XB[5], XS[5], XM1.y);
        FSTEPD(XA[6], XB[6], XS[6], XM1.z);
        FSTEPD(XA[7], XB[7], XS[7], XM1.w);
        RENORMD();
        LOADD8(XA, XB, XS, XM0, XM1, 16);
        DFCH8(YA, YB, YS, YM0, YM1);                     // chunk 1 (t 8..15)
        for (int cp = 1; cp < 15; ++cp) {
            LOADD8(YA, YB, YS, YM0, YM1, 16 * cp + 8);
            DFCH8(XA, XB, XS, XM0, XM1);
            LOADD8(XA, XB, XS, XM0, XM1, 16 * cp + 16);
            DFCH8(YA, YB, YS, YM0, YM1);
        }
        LOADD8(YA, YB, YS, YM0, YM1, 248);
        DFCH8(XA, XB, XS, XM0, XM1);
        DFCH8(YA, YB, YS, YM0, YM1);                     // -> alpha_255
        float* rec = recs + (size_t)seq * REC;
#pragma unroll
        for (int k = 0; k < 4; ++k) {
            rec[4 * h + k]     = W[k];
            rec[8 + 4 * h + k] = W[4 + k];
        }
        if (h == 0) { rec[16] = W[8]; rec[17] = Z; }
    } else {
        LOADD8(XA, XB, XS, XM0, XM1, 504);
        LOADD8(YA, YB, YS, YM0, YM1, 496);
        {   // init: v_511 = exp(end)
            f4u e0 = *(const f4u*)(endt + 4 * h);
            f4u e1 = *(const f4u*)(endt + 8 + 4 * h);
            W[0] = __expf(e0.x); W[1] = __expf(e0.y);
            W[2] = __expf(e0.z); W[3] = __expf(e0.w);
            W[4] = __expf(e1.x); W[5] = __expf(e1.y);
            W[6] = __expf(e1.z); W[7] = __expf(e1.w);
            W[8] = h ? 0.0f : __expf(endt[16]);
            W16SWAPW();
        }
        DBCH8(XA, XB, XS, XM0, XM1);                     // t 511..504
        LOADD8(XA, XB, XS, XM0, XM1, 488);
        DBCH8(YA, YB, YS, YM0, YM1);                     // t 503..496
        for (int cp = 1; cp < 15; ++cp) {
            LOADD8(YA, YB, YS, YM0, YM1, 496 - 16 * cp);
            DBCH8(XA, XB, XS, XM0, XM1);
            LOADD8(XA, XB, XS, XM0, XM1, 488 - 16 * cp);
            DBCH8(YA, YB, YS, YM0, YM1);
        }
        LOADD8(YA, YB, YS, YM0, YM1, 256);
        DBCH8(XA, XB, XS, XM0, XM1);
        DBCH8(YA, YB, YS, YM0, YM1);                     // -> v_255
        float* rec = recs + (size_t)seq * REC;
#pragma unroll
        for (int k = 0; k < 4; ++k) {
            rec[18 + 4 * h + k] = W[k];
            rec[26 + 4 * h + k] = W[4 + k];
        }
        if (h == 0) { rec[34] = W[8]; rec[35] = Z; }
    }
}

// ======================= FALLBACK (r8, validated) =======================

#define W16SWAP() do {                                                       \
    auto rw_ = __builtin_amdgcn_permlane32_swap(__float_as_uint(W8),         \
                                                __float_as_uint(W8),         \
                                                false, false);               \
    w16 = __uint_as_float(rw_[0]);                                           \
} while (0)

#define LOADK8(Q0, Q1, SS, MA, MB, T0_) do {                                 \
    const float* bp_ = ip + (size_t)(T0_) * T_;                              \
    _Pragma("unroll") for (int u_ = 0; u_ < 8; ++u_) {                       \
        Q0[u_] = *(const f4u*)(bp_ + u_ * T_ + 4 * h);                       \
        Q1[u_] = *(const f4u*)(bp_ + u_ * T_ + 8 + 4 * h);                   \
        SS[u_] = bp_[u_ * T_ + 16];                                          \
    }                                                                        \
    MA = *(const int4*)(mp + (T0_));                                         \
    MB = *(const int4*)(mp + (T0_) + 4);                                     \
} while (0)

#define FSTEP(Q0u, Q1u, Su, Mu) do {                                         \
    frag_u Bf_;                                                              \
    PACKB(W0,W1,W2,W3,W4,W5,W6,W7, Bf_);                                     \
    v16f acc_ = __builtin_amdgcn_mfma_f32_32x32x16_bf16(A1.v, Bf_.v, zacc,0,0,0); \
    float d0_=__expf((Q0u).x), d1_=__expf((Q0u).y);                          \
    float d2_=__expf((Q0u).z), d3_=__expf((Q0u).w);                          \
    float d4_=__expf((Q1u).x), d5_=__expf((Q1u).y);                          \
    float d6_=__expf((Q1u).z), d7_=__expf((Q1u).w);                          \
    float d8_=__expf(Su);                                                    \
    bool bm_ = (Mu) != 0;                                                    \
    float n0_ = fmaf(E16[0], w16, acc_[0]) * d0_;                            \
    float n1_ = fmaf(E16[1], w16, acc_[1]) * d1_;                            \
    float n2_ = fmaf(E16[2], w16, acc_[2]) * d2_;                            \
    float n3_ = fmaf(E16[3], w16, acc_[3]) * d3_;                            \
    float n4_ = fmaf(E16[4], w16, acc_[4]) * d4_;                            \
    float n5_ = fmaf(E16[5], w16, acc_[5]) * d5_;                            \
    float n6_ = fmaf(E16[6], w16, acc_[6]) * d6_;                            \
    float n7_ = fmaf(E16[7], w16, acc_[7]) * d7_;                            \
    float n8_ = fmaf(E16[8], w16, acc_[8]) * d8_;                            \
    W0=bm_?n0_:W0; W1=bm_?n1_:W1; W2=bm_?n2_:W2; W3=bm_?n3_:W3;              \
    W4=bm_?n4_:W4; W5=bm_?n5_:W5; W6=bm_?n6_:W6; W7=bm_?n7_:W7;              \
    W8=bm_?n8_:W8;                                                           \
    W16SWAP();                                                               \
} while (0)

#define BSTEP(Q0u, Q1u, Su, Mu) do {                                         \
    float d0_=__expf((Q0u).x), d1_=__expf((Q0u).y);                          \
    float d2_=__expf((Q0u).z), d3_=__expf((Q0u).w);                          \
    float d4_=__expf((Q1u).x), d5_=__expf((Q1u).y);                          \
    float d6_=__expf((Q1u).z), d7_=__expf((Q1u).w);                          \
    float d8_=__expf(Su);                                                    \
    float U16_ = w16 * d8_;                                                  \
    frag_u Bf_;                                                              \
    PACKB(W0*d0_, W1*d1_, W2*d2_, W3*d3_,                                    \
          W4*d4_, W5*d5_, W6*d6_, W7*d7_, Bf_);                              \
    v16f acc_ = __builtin_amdgcn_mfma_f32_32x32x16_bf16(A1.v, Bf_.v, zacc,0,0,0); \
    bool bm_ = (Mu) != 0;                                                    \
    float n0_ = fmaf(E16[0], U16_, acc_[0]);                                 \
    float n1_ = fmaf(E16[1], U16_, acc_[1]);                                 \
    float n2_ = fmaf(E16[2], U16_, acc_[2]);                                 \
    float n3_ = fmaf(E16[3], U16_, acc_[3]);                                 \
    float n4_ = fmaf(E16[4], U16_, acc_[4]);                                 \
    float n5_ = fmaf(E16[5], U16_, acc_[5]);                                 \
    float n6_ = fmaf(E16[6], U16_, acc_[6]);                                 \
    float n7_ = fmaf(E16[7], U16_, acc_[7]);                                 \
    float n8_ = fmaf(E16[8], U16_, acc_[8]);                                 \
    W0=bm_?n0_:W0; W1=bm_?n1_:W1; W2=bm_?n2_:W2; W3=bm_?n3_:W3;              \
    W4=bm_?n4_:W4; W5=bm_?n5_:W5; W6=bm_?n6_:W6; W7=bm_?n7_:W7;              \
    W8=bm_?n8_:W8;                                                           \
    W16SWAP();                                                               \
} while (0)

#define RENORM() do {                                                        \
    float M_ = fmaxf(fmaxf(fmaxf(W0,W1),fmaxf(W2,W3)),                       \
                     fmaxf(fmaxf(W4,W5),fmaxf(fmaxf(W6,W7),W8)));            \
    auto rm_ = __builtin_amdgcn_permlane32_swap(__float_as_uint(M_),         \
                                                __float_as_uint(M_),         \
                                                false, false);               \
    M_ = fmaxf(__uint_as_float(rm_[0]), __uint_as_float(rm_[1]));            \
    float r_ = 1.0f / M_;                                                    \
    Z += __logf(M_);                                                         \
    W0*=r_; W1*=r_; W2*=r_; W3*=r_; W4*=r_;                                  \
    W5*=r_; W6*=r_; W7*=r_; W8*=r_; w16*=r_;                                 \
} while (0)

#define FCH8(Q0a, Q1a, Sa, Ma, Mb) do {                                      \
    FSTEP(Q0a[0], Q1a[0], Sa[0], (Ma).x);                                    \
    FSTEP(Q0a[1], Q1a[1], Sa[1], (Ma).y);                                    \
    FSTEP(Q0a[2], Q1a[2], Sa[2], (Ma).z);                                    \
    FSTEP(Q0a[3], Q1a[3], Sa[3], (Ma).w);                                    \
    RENORM();                                                                \
    FSTEP(Q0a[4], Q1a[4], Sa[4], (Mb).x);                                    \
    FSTEP(Q0a[5], Q1a[5], Sa[5], (Mb).y);                                    \
    FSTEP(Q0a[6], Q1a[6], Sa[6], (Mb).z);                                    \
    FSTEP(Q0a[7], Q1a[7], Sa[7], (Mb).w);                                    \
    RENORM();                                                                \
} while (0)

#define BCH8(Q0a, Q1a, Sa, Ma, Mb) do {                                      \
    BSTEP(Q0a[7], Q1a[7], Sa[7], (Mb).w);                                    \
    BSTEP(Q0a[6], Q1a[6], Sa[6], (Mb).z);                                    \
    BSTEP(Q0a[5], Q1a[5], Sa[5], (Mb).y);                                    \
    BSTEP(Q0a[4], Q1a[4], Sa[4], (Mb).x);                                    \
    RENORM();                                                                \
    BSTEP(Q0a[3], Q1a[3], Sa[3], (Ma).w);                                    \
    BSTEP(Q0a[2], Q1a[2], Sa[2], (Ma).z);                                    \
    BSTEP(Q0a[1], Q1a[1], Sa[1], (Ma).y);                                    \
    BSTEP(Q0a[0], Q1a[0], Sa[0], (Ma).x);                                    \
    RENORM();                                                                \
} while (0)

__global__ __launch_bounds__(64) void crf_fused_fb(
    const float* __restrict__ inputs, const int* __restrict__ tags,
    const int* __restrict__ mask, const float* __restrict__ trans,
    const float* __restrict__ startt, const float* __restrict__ endt,
    float* __restrict__ ws)
{
    __shared__ float tl[T_ * T_];
    const int lane = (int)threadIdx.x;
    const int bid = (int)blockIdx.x;
    for (int k = lane; k < T_ * T_; k += 64) tl[k] = trans[k];
    __syncthreads();

    if (bid < MAINB) {
        const bool isF = (bid < FWDB);
        const int h = lane >> 5;
        const int col = lane & 31;
        const int seq = (isF ? bid : bid - FWDB) * 32 + col;

        frag_u A1;
#pragma unroll
        for (int wd = 0; wd < 4; ++wd) {
            const int k0 = 8 * h + 2 * wd, k1 = k0 + 1;
            float e0 = 0.0f, e1 = 0.0f;
            if (col < 17) {
                e0 = isF ? __expf(tl[k0 * T_ + col]) : __expf(tl[col * T_ + k0]);
                e1 = isF ? __expf(tl[k1 * T_ + col]) : __expf(tl[col * T_ + k1]);
            }
            A1.u[wd] = pkbf(e0, e1);
        }
        float E16[9];
#pragma unroll
        for (int k = 0; k < 4; ++k) {
            const int r0 = 4 * h + k, r1 = 8 + 4 * h + k;
            E16[k]     = __expf(isF ? tl[16 * T_ + r0] : tl[r0 * T_ + 16]);
            E16[4 + k] = __expf(isF ? tl[16 * T_ + r1] : tl[r1 * T_ + 16]);
        }
        E16[8] = (h == 0) ? __expf(tl[16 * T_ + 16]) : 0.0f;

        v16f zacc;
#pragma unroll
        for (int r = 0; r < 16; ++r) zacc[r] = 0.0f;

        const float* ip = inputs + (size_t)seq * (S_ * T_);
        const int*   mp = mask + (size_t)seq * S_;

        float W0, W1, W2, W3, W4, W5, W6, W7, W8, w16, Z = 0.0f;
        f4u X0[8], X1[8]; float XS[8]; int4 XM0, XM1;
        f4u Y0[8], Y1[8]; float YS[8]; int4 YM0, YM1;

        if (isF) {
            LOADK8(X0, X1, XS, XM0, XM1, 0);
            LOADK8(Y0, Y1, YS, YM0, YM1, 8);
            {
                f4u s0 = *(const f4u*)(startt + 4 * h);
                f4u s1 = *(const f4u*)(startt + 8 + 4 * h);
                W0 = __expf(X0[0].x + s0.x); W1 = __expf(X0[0].y + s0.y);
                W2 = __expf(X0[0].z + s0.z); W3 = __expf(X0[0].w + s0.w);
                W4 = __expf(X1[0].x + s1.x); W5 = __expf(X1[0].y + s1.y);
                W6 = __expf(X1[0].z + s1.z); W7 = __expf(X1[0].w + s1.w);
                W8 = h ? 0.0f : __expf(XS[0] + startt[16]);
                W16SWAP();
            }
            FSTEP(X0[1], X1[1], XS[1], XM0.y);
            FSTEP(X0[2], X1[2], XS[2], XM0.z);
            FSTEP(X0[3], X1[3], XS[3], XM0.w);
            RENORM();
            FSTEP(X0[4], X1[4], XS[4], XM1.x);
            FSTEP(X0[5], X1[5], XS[5], XM1.y);
            FSTEP(X0[6], X1[6], XS[6], XM1.z);
            FSTEP(X0[7], X1[7], XS[7], XM1.w);
            RENORM();
            LOADK8(X0, X1, XS, XM0, XM1, 16);
            FCH8(Y0, Y1, YS, YM0, YM1);
            for (int cp = 1; cp < 15; ++cp) {
                LOADK8(Y0, Y1, YS, YM0, YM1, 16 * cp + 8);
                FCH8(X0, X1, XS, XM0, XM1);
                LOADK8(X0, X1, XS, XM0, XM1, 16 * cp + 16);
                FCH8(Y0, Y1, YS, YM0, YM1);
            }
            LOADK8(Y0, Y1, YS, YM0, YM1, 248);
            FCH8(X0, X1, XS, XM0, XM1);
            FCH8(Y0, Y1, YS, YM0, YM1);
            float* rec = ws + (size_t)seq * REC;
            rec[4*h+0] = W0; rec[4*h+1] = W1; rec[4*h+2] = W2; rec[4*h+3] = W3;
            rec[8+4*h+0] = W4; rec[8+4*h+1] = W5; rec[8+4*h+2] = W6; rec[8+4*h+3] = W7;
            if (h == 0) { rec[16] = W8; rec[17] = Z; }
        } else {
            LOADK8(X0, X1, XS, XM0, XM1, 504);
            LOADK8(Y0, Y1, YS, YM0, YM1, 496);
            {
                f4u e0 = *(const f4u*)(endt + 4 * h);
                f4u e1 = *(const f4u*)(endt + 8 + 4 * h);
                W0 = __expf(e0.x); W1 = __expf(e0.y);
                W2 = __expf(e0.z); W3 = __expf(e0.w);
                W4 = __expf(e1.x); W5 = __expf(e1.y);
                W6 = __expf(e1.z); W7 = __expf(e1.w);
                W8 = h ? 0.0f : __expf(endt[16]);
                W16SWAP();
            }
            BCH8(X0, X1, XS, XM0, XM1);
            LOADK8(X0, X1, XS, XM0, XM1, 488);
            BCH8(Y0, Y1, YS, YM0, YM1);
            for (int cp = 1; cp < 15; ++cp) {
                LOADK8(Y0, Y1, YS, YM0, YM1, 496 - 16 * cp);
                BCH8(X0, X1, XS, XM0, XM1);
                LOADK8(X0, X1, XS, XM0, XM1, 488 - 16 * cp);
                BCH8(Y0, Y1, YS, YM0, YM1);
            }
            LOADK8(Y0, Y1, YS, YM0, YM1, 256);
            BCH8(X0, X1, XS, XM0, XM1);
            BCH8(Y0, Y1, YS, YM0, YM1);
            float* rec = ws + (size_t)seq * REC;
            rec[18+4*h+0] = W0; rec[18+4*h+1] = W1;
            rec[18+4*h+2] = W2; rec[18+4*h+3] = W3;
            rec[18+8+4*h+0] = W4; rec[18+8+4*h+1] = W5;
            rec[18+8+4*h+2] = W6; rec[18+8+4*h+3] = W7;
            if (h == 0) { rec[34] = W8; rec[35] = Z; }
        }
    } else {
        helper_score(bid - MAINB, lane, tags, mask, inputs, startt, endt, tl, ws);
    }
}

// ---- final combine (shared): recs base passed in ----
__global__ __launch_bounds__(256) void crf_final(const float* __restrict__ recs,
                                                 float* __restrict__ out)
{
    __shared__ float sm[256];
    const int tid = (int)threadIdx.x;
    float a = 0.0f;
    for (int s = tid; s < B_; s += 256) {
        const float* r = recs + (size_t)s * REC;
        float dot = 0.0f;
#pragma unroll
        for (int i = 0; i < T_; ++i) dot = fmaf(r[i], r[18 + i], dot);
        a += r[36] - (r[17] + r[35] + __logf(dot));
    }
    sm[tid] = a;
    __syncthreads();
    for (int k = 128; k >= 1; k >>= 1) {
        if (tid < k) sm[tid] += sm[tid + k];
        __syncthreads();
    }
    if (tid == 0) out[0] = sm[0];
}

extern "C" void kernel_launch(void* const* d_in, const int* in_sizes, int n_in,
                              void* d_out, int out_size, void* d_ws, size_t ws_size,
                              hipStream_t stream)
{
    const float* inputs = (const float*)d_in[0];
    const int*   tags   = (const int*)d_in[1];
    const int*   mask   = (const int*)d_in[2];
    const float* trans  = (const float*)d_in[3];
    const float* startt = (const float*)d_in[4];
    const float* endt   = (const float*)d_in[5];
    float* out = (float*)d_out;

    const size_t dbytes = (size_t)B_ * S_ * DRO * 2;          // 41.94 MB
    const size_t need = dbytes + (size_t)B_ * REC * 4;

    if (ws_size >= need) {
        unsigned short* dws = (unsigned short*)d_ws;
        float* recs = (float*)((char*)d_ws + dbytes);
        crf_prep<<<PREPCB + B_, 64, 0, stream>>>(inputs, tags, mask, trans,
                                                 startt, endt, recs, dws);
        crf_main2<<<MAINB, 64, 0, stream>>>(dws, mask, trans, startt, endt, recs);
        crf_final<<<1, 256, 0, stream>>>(recs, out);
    } else {
        float* ws = (float*)d_ws;
        crf_fused_fb<<<MAINB + B_, 64, 0, stream>>>(inputs, tags, mask, trans,
                                                    startt, endt, ws);
        crf_final<<<1, 256, 0, stream>>>(ws, out);
    }
}